// Round 5
// baseline (790.886 us; speedup 1.0000x reference)
//
#include <hip/hip_runtime.h>

// Problem constants (from reference)
#define NVOX 150000
#define NPAD 150016          // 2344 * 64 row tiles
#define CCH  256
#define ZROW NVOX            // zero row for -1 / padded gathers (pad rows zeroed)
#define GRIDX 2344           // NPAD/64, = 8 * 293
#define CAP  4608            // per-tap pair capacity: mean ~4060, std ~63 (8.6 sigma)
#define CAPP 4672            // Ytap slots per tap (73*64); slots >= count are ZERO rows
#define ZSLOT 4671           // guaranteed-zero slot (count <= CAP < ZSLOT)

typedef __attribute__((ext_vector_type(8))) short bfrag_t;   // 8 bf16 = 4 VGPRs
typedef __attribute__((ext_vector_type(4))) float accfrag_t; // 4 fp32

__device__ __forceinline__ void async_copy16(const void* g, void* l) {
  __builtin_amdgcn_global_load_lds(
      (const __attribute__((address_space(1))) void*)g,
      (__attribute__((address_space(3))) void*)l, 16, 0, 0);
}

__device__ __forceinline__ unsigned short f2bf(float x) {
  unsigned int u = __float_as_uint(x);
  unsigned int r = (u + 0x7FFFu + ((u >> 16) & 1u)) >> 16;  // RNE
  return (unsigned short)r;
}

__device__ __forceinline__ float bf2f(unsigned short u) {
  return __uint_as_float(((unsigned int)u) << 16);
}

// ---- feats fp32 -> bf16 (padded, pad rows zeroed) ----
__global__ __launch_bounds__(256) void cvt_feats_kernel(
    const float* __restrict__ f, unsigned short* __restrict__ o) {
  int t = blockIdx.x * 256 + threadIdx.x;        // 8 elements per thread
  int row = t >> 5;                              // 32 threads per 256-ch row
  bfrag_t pack;
  if (row < NVOX) {
    const float4* fp = (const float4*)f;
    float4 a = fp[2 * t];
    float4 b = fp[2 * t + 1];
    float v[8] = {a.x, a.y, a.z, a.w, b.x, b.y, b.z, b.w};
#pragma unroll
    for (int i = 0; i < 8; ++i) pack[i] = (short)f2bf(v[i]);
  } else {
#pragma unroll
    for (int i = 0; i < 8; ++i) pack[i] = 0;
  }
  *(bfrag_t*)(o + (size_t)t * 8) = pack;
}

// ---- weights fp32 [3][cin][cout] -> bf16 transposed Wt[9][cout][cin] ----
__global__ __launch_bounds__(256) void cvt_w_kernel(
    const float* __restrict__ w1, const float* __restrict__ w2,
    const float* __restrict__ w3, unsigned short* __restrict__ o) {
  int t = blockIdx.x * 256 + threadIdx.x;  // 9*65536 total
  int g9 = t >> 16;                        // conv*3+tap, 0..8
  int idx = t & 65535;
  int n = idx >> 8, k = idx & 255;
  const float* w = (g9 < 3) ? w1 : ((g9 < 6) ? w2 : w3);
  int tap = (g9 < 3) ? g9 : ((g9 < 6) ? g9 - 3 : g9 - 6);
  o[t] = f2bf(w[(tap * 256 + k) * 256 + n]);
}

// ---- init: sidx = ZSLOT (points at a guaranteed-zero Ytap row), tcnt = 0 ----
__global__ __launch_bounds__(256) void init_kernel(
    int* __restrict__ sidx, int* __restrict__ tcnt) {
  int t = blockIdx.x * 256 + threadIdx.x;  // grid sized exactly 6*NPAD
  sidx[t] = ZSLOT;
  if (t < 6) tcnt[t] = 0;
}

// ---- build per-tap compacted pair lists ----
// tap order: 0:x-1 1:x+1 2:y-1 3:y+1 4:z-1 5:z+1
// pairs[tap][p] = source row; sidx[tap][row] = p (slot), else ZSLOT.
__global__ __launch_bounds__(256) void build_kernel(
    const int* __restrict__ nbrx, const int* __restrict__ nbry,
    const int* __restrict__ nbrz,
    int* __restrict__ sidx, int* __restrict__ pairs, int* __restrict__ tcnt) {
  __shared__ int wcnt[4], wbase[4];
  int r = blockIdx.x * 256 + threadIdx.x;
  const int lane = threadIdx.x & 63, w = threadIdx.x >> 6;
  bool act = (r < NVOX);
  int nb[6];
  nb[0] = act ? nbrx[r * 3]     : -1;
  nb[1] = act ? nbrx[r * 3 + 2] : -1;
  nb[2] = act ? nbry[r * 3]     : -1;
  nb[3] = act ? nbry[r * 3 + 2] : -1;
  nb[4] = act ? nbrz[r * 3]     : -1;
  nb[5] = act ? nbrz[r * 3 + 2] : -1;
  for (int t = 0; t < 6; ++t) {
    bool h = nb[t] >= 0;
    unsigned long long b = __ballot(h);
    int pfx = __popcll(b & ((1ull << lane) - 1ull));
    if (lane == 0) wcnt[w] = __popcll(b);
    __syncthreads();
    if (threadIdx.x == 0) {
      int tot = wcnt[0] + wcnt[1] + wcnt[2] + wcnt[3];
      int base = tot ? atomicAdd(&tcnt[t], tot) : 0;
      wbase[0] = base;
      wbase[1] = base + wcnt[0];
      wbase[2] = base + wcnt[0] + wcnt[1];
      wbase[3] = base + wcnt[0] + wcnt[1] + wcnt[2];
    }
    __syncthreads();
    if (h) {
      int p = wbase[w] + pfx;
      if (p < CAP) {
        pairs[t * CAP + p] = nb[t];
        sidx[t * NPAD + r] = p;
      }
    }
    __syncthreads();  // WAR on wcnt/wbase before next tap
  }
}

// ---- sparse tap GEMM: Ytap[tap][slot][:] = f16[src] . W[tap]  (bf16 out) ----
// grid (CAPP/64, 6); slots >= count gather ZROW -> zero output rows (incl ZSLOT)
__global__ __launch_bounds__(512, 2) void sparse_kernel(
    const unsigned short* __restrict__ F16, const unsigned short* __restrict__ Wt,
    const int* __restrict__ pairs, const int* __restrict__ tcnt,
    unsigned short* __restrict__ Ytap) {
  __shared__ unsigned short As[64 * 256];  // 32 KB, XOR-swizzled
  const int tid = threadIdx.x;
  const int w = tid >> 6, lane = tid & 63;
  const int m = lane & 15, quad = lane >> 4;
  const int half = lane >> 5;
  const int lrb = w << 3;
  const int tap = blockIdx.y;
  const int p0 = blockIdx.x * 64;
  const int cnt0 = tcnt[tap];
  const int cnt = cnt0 < CAP ? cnt0 : CAP;

  // stage gathered source rows (slots past count -> ZROW -> zeros)
#pragma unroll
  for (int iss = 0; iss < 4; ++iss) {
    int lr = lrb + (iss << 1) + half;
    int p = p0 + lr;
    int src = (p < cnt) ? pairs[tap * CAP + p] : -1;
    int srow = (src >= 0) ? src : ZROW;
    int clog = (lane & 31) ^ (lr & 31);
    async_copy16(F16 + ((size_t)srow << 8) + (clog << 3),
                 (char*)As + ((size_t)(lrb + (iss << 1)) << 9));
  }
  __syncthreads();

  const int g9 = (tap >> 1) * 3 + ((tap & 1) << 1);  // conv*3 + {0,2}
  const unsigned short* Wtap = Wt + ((size_t)g9 << 16);
  accfrag_t acc[4][2];
#pragma unroll
  for (int mt = 0; mt < 4; ++mt)
#pragma unroll
    for (int nt = 0; nt < 2; ++nt) acc[mt][nt] = (accfrag_t){0.f, 0.f, 0.f, 0.f};

#pragma unroll
  for (int ks = 0; ks < 8; ++ks) {
    bfrag_t a[4], bb[2];
#pragma unroll
    for (int mt = 0; mt < 4; ++mt) {
      int row = mt * 16 + m;
      int phys = ((ks << 2) + quad) ^ (row & 31);
      a[mt] = *(const bfrag_t*)((const char*)As + row * 512 + phys * 16);
    }
#pragma unroll
    for (int nt = 0; nt < 2; ++nt) {
      int col = (w << 5) + nt * 16 + m;
      bb[nt] = *(const bfrag_t*)(Wtap + col * 256 + (ks << 5) + (quad << 3));
    }
#pragma unroll
    for (int mt = 0; mt < 4; ++mt)
#pragma unroll
      for (int nt = 0; nt < 2; ++nt)
        acc[mt][nt] = __builtin_amdgcn_mfma_f32_16x16x32_bf16(
            a[mt], bb[nt], acc[mt][nt], 0, 0, 0);
  }

#pragma unroll
  for (int mt = 0; mt < 4; ++mt)
#pragma unroll
    for (int r = 0; r < 4; ++r) {
      int slot = p0 + mt * 16 + quad * 4 + r;
#pragma unroll
      for (int nt = 0; nt < 2; ++nt) {
        int col = (w << 5) + nt * 16 + m;
        Ytap[((size_t)tap * CAPP + slot) * 256 + col] = f2bf(acc[mt][nt][r]);
      }
    }
}

// ---- main: dense center GEMM (A staged ONCE, 3 convs reuse it) + BRANCH-FREE
//      sparse adds (zero-slot) + BN+sigmoid + gate. ONE barrier per block. ----
__global__ __launch_bounds__(512, 2) void recon_kernel(
    const unsigned short* __restrict__ F16, const float* __restrict__ F32,
    const unsigned short* __restrict__ Wt,
    const unsigned short* __restrict__ Ytap, const int* __restrict__ sidx,
    const float* __restrict__ g1, const float* __restrict__ b1,
    const float* __restrict__ g2, const float* __restrict__ b2,
    const float* __restrict__ g3, const float* __restrict__ b3,
    float* __restrict__ out) {
  __shared__ unsigned short As[64 * 256];  // 32 KB, XOR-swizzled
  const int tid = threadIdx.x;
  const int w = tid >> 6, lane = tid & 63;
  const int m = lane & 15, quad = lane >> 4;
  const int half = lane >> 5;
  const int lrb = w << 3;
  // XCD-aware bijective swizzle (2344 = 8*293)
  const int bid = blockIdx.x;
  const int bsw = (bid & 7) * (GRIDX / 8) + (bid >> 3);
  const int m0 = bsw * 64;
  const float RSQ = 0.9999950000374998f;  // rsqrt(1+1e-5)

  accfrag_t sum[4][2];
#pragma unroll
  for (int mt = 0; mt < 4; ++mt)
#pragma unroll
    for (int nt = 0; nt < 2; ++nt) sum[mt][nt] = (accfrag_t){0.f, 0.f, 0.f, 0.f};

  // stage identity rows once (pad rows are zeroed in F16)
#pragma unroll
  for (int iss = 0; iss < 4; ++iss) {
    int lr = lrb + (iss << 1) + half;
    int srow = m0 + lr;
    int clog = (lane & 31) ^ (lr & 31);
    async_copy16(F16 + ((size_t)srow << 8) + (clog << 3),
                 (char*)As + ((size_t)(lrb + (iss << 1)) << 9));
  }
  __syncthreads();  // only barrier in the kernel

  for (int conv = 0; conv < 3; ++conv) {
    const unsigned short* Wc = Wt + ((size_t)(conv * 3 + 1) << 16);  // center
    accfrag_t acc[4][2];
#pragma unroll
    for (int mt = 0; mt < 4; ++mt)
#pragma unroll
      for (int nt = 0; nt < 2; ++nt) acc[mt][nt] = (accfrag_t){0.f, 0.f, 0.f, 0.f};

    __builtin_amdgcn_s_setprio(1);
#pragma unroll
    for (int ks = 0; ks < 8; ++ks) {
      bfrag_t a[4], bb[2];
#pragma unroll
      for (int mt = 0; mt < 4; ++mt) {
        int row = mt * 16 + m;
        int phys = ((ks << 2) + quad) ^ (row & 31);
        a[mt] = *(const bfrag_t*)((const char*)As + row * 512 + phys * 16);
      }
#pragma unroll
      for (int nt = 0; nt < 2; ++nt) {
        int col = (w << 5) + nt * 16 + m;
        bb[nt] = *(const bfrag_t*)(Wc + col * 256 + (ks << 5) + (quad << 3));
      }
#pragma unroll
      for (int mt = 0; mt < 4; ++mt)
#pragma unroll
        for (int nt = 0; nt < 2; ++nt)
          acc[mt][nt] = __builtin_amdgcn_mfma_f32_16x16x32_bf16(
              a[mt], bb[nt], acc[mt][nt], 0, 0, 0);
    }
    __builtin_amdgcn_s_setprio(0);

    // epilogue: BRANCH-FREE sparse adds (zero-slot), BN + sigmoid, accumulate
    const float* gp = (conv == 0) ? g1 : ((conv == 1) ? g2 : g3);
    const float* bp = (conv == 0) ? b1 : ((conv == 1) ? b2 : b3);
    float sc[2], bi[2];
#pragma unroll
    for (int nt = 0; nt < 2; ++nt) {
      int c = (w << 5) + nt * 16 + m;
      sc[nt] = gp[c] * RSQ;
      bi[nt] = bp[c];
    }
    const int* sxm = sidx + (size_t)(2 * conv) * NPAD;
    const int* sxp = sidx + (size_t)(2 * conv + 1) * NPAD;
    const unsigned short* Ym = Ytap + (size_t)(2 * conv) * CAPP * 256;
    const unsigned short* Yp = Ytap + (size_t)(2 * conv + 1) * CAPP * 256;
#pragma unroll
    for (int mt = 0; mt < 4; ++mt) {
      int smv[4], spv[4];
#pragma unroll
      for (int r = 0; r < 4; ++r) {
        int row = m0 + mt * 16 + quad * 4 + r;
        smv[r] = sxm[row];
        spv[r] = sxp[row];
      }
#pragma unroll
      for (int r = 0; r < 4; ++r) {
#pragma unroll
        for (int nt = 0; nt < 2; ++nt) {
          int c = (w << 5) + nt * 16 + m;
          float y = acc[mt][nt][r]
                  + bf2f(Ym[(size_t)smv[r] * 256 + c])
                  + bf2f(Yp[(size_t)spv[r] * 256 + c]);
          sum[mt][nt][r] += 1.0f / (1.0f + __expf(-(y * sc[nt] + bi[nt])));
        }
      }
    }
  }

  // final gate: out = sum * feats (fp32)
#pragma unroll
  for (int mt = 0; mt < 4; ++mt)
#pragma unroll
    for (int r = 0; r < 4; ++r) {
      int row = m0 + mt * 16 + quad * 4 + r;
      if (row < NVOX) {
#pragma unroll
        for (int nt = 0; nt < 2; ++nt) {
          int c = (w << 5) + nt * 16 + m;
          size_t off = ((size_t)row << 8) + c;
          out[off] = sum[mt][nt][r] * F32[off];
        }
      }
    }
}

extern "C" void kernel_launch(void* const* d_in, const int* in_sizes, int n_in,
                              void* d_out, int out_size, void* d_ws, size_t ws_size,
                              hipStream_t stream) {
  const float* feats = (const float*)d_in[0];
  const float* w1 = (const float*)d_in[1];
  const float* w2 = (const float*)d_in[2];
  const float* w3 = (const float*)d_in[3];
  const float* g1 = (const float*)d_in[4];
  const float* b1 = (const float*)d_in[5];
  const float* g2 = (const float*)d_in[6];
  const float* b2 = (const float*)d_in[7];
  const float* g3 = (const float*)d_in[8];
  const float* b3 = (const float*)d_in[9];
  const int* nbrx = (const int*)d_in[10];
  const int* nbry = (const int*)d_in[11];
  const int* nbrz = (const int*)d_in[12];
  float* out = (float*)d_out;

  // ws layout (all offsets 64B-aligned):
  //   F16   : NPAD*256 bf16             = 76.81 MB
  //   Wt    : 9*65536 bf16              =  1.18 MB
  //   Ytap  : 6*CAPP*256 bf16           = 14.36 MB
  //   sidx  : 6*NPAD int32              =  3.60 MB
  //   pairs : 6*CAP int32               =  0.11 MB
  //   tcnt  : 6 int32 (+pad)
  unsigned short* F16 = (unsigned short*)d_ws;
  unsigned short* Wt = F16 + (size_t)NPAD * CCH;
  unsigned short* Ytap = Wt + (size_t)9 * 65536;
  int* sidx = (int*)(Ytap + (size_t)6 * CAPP * 256);
  int* pairs = sidx + (size_t)6 * NPAD;
  int* tcnt = pairs + (size_t)6 * CAP;

  cvt_feats_kernel<<<NPAD * CCH / 8 / 256, 256, 0, stream>>>(feats, F16);
  cvt_w_kernel<<<9 * 65536 / 256, 256, 0, stream>>>(w1, w2, w3, Wt);
  init_kernel<<<6 * NPAD / 256, 256, 0, stream>>>(sidx, tcnt);
  build_kernel<<<NPAD / 256, 256, 0, stream>>>(nbrx, nbry, nbrz, sidx, pairs, tcnt);
  dim3 sgrid(CAPP / 64, 6);
  sparse_kernel<<<sgrid, 512, 0, stream>>>(F16, Wt, pairs, tcnt, Ytap);
  dim3 grid(GRIDX);
  recon_kernel<<<grid, 512, 0, stream>>>(F16, feats, Wt, Ytap, sidx,
                                         g1, b1, g2, b2, g3, b3, out);
}

// Round 6
// 625.449 us; speedup vs baseline: 1.2645x; 1.2645x over previous
//
#include <hip/hip_runtime.h>

// Problem constants (from reference)
#define NVOX 150000
#define NPAD 150016          // 2344 * 64 row tiles
#define CCH  256
#define ZROW NVOX            // zero row for -1 / padded gathers (pad rows zeroed)
#define GRIDX 2344           // NPAD/64, = 8 * 293
#define CAP  4608            // per-tap pair capacity: mean ~4060, std ~63 (8.6 sigma)
#define CAPP 4672            // Ytap slots per tap (73*64); slots >= count are ZERO rows
#define ZSLOT 4671           // guaranteed-zero slot (count <= CAP < ZSLOT)
#define HCAP 32              // per-(block,conv) hit capacity (mean 3.4, 32 >> 9 sigma)

typedef __attribute__((ext_vector_type(8))) short bfrag_t;   // 8 bf16 = 4 VGPRs
typedef __attribute__((ext_vector_type(4))) float accfrag_t; // 4 fp32

__device__ __forceinline__ void async_copy16(const void* g, void* l) {
  __builtin_amdgcn_global_load_lds(
      (const __attribute__((address_space(1))) void*)g,
      (__attribute__((address_space(3))) void*)l, 16, 0, 0);
}

__device__ __forceinline__ unsigned short f2bf(float x) {
  unsigned int u = __float_as_uint(x);
  unsigned int r = (u + 0x7FFFu + ((u >> 16) & 1u)) >> 16;  // RNE
  return (unsigned short)r;
}

__device__ __forceinline__ float bf2f(unsigned short u) {
  return __uint_as_float(((unsigned int)u) << 16);
}

// ---- fused prep: feats fp32->bf16 (padded, pad zeroed) + weights transpose
//      + tcnt zeroing. One launch instead of three. ----
__global__ __launch_bounds__(256) void prep_kernel(
    const float* __restrict__ f, unsigned short* __restrict__ o,
    const float* __restrict__ w1, const float* __restrict__ w2,
    const float* __restrict__ w3, unsigned short* __restrict__ wo,
    int* __restrict__ tcnt) {
  int b = blockIdx.x;
  if (b < NPAD * CCH / 8 / 256) {
    int t = b * 256 + threadIdx.x;               // 8 elements per thread
    int row = t >> 5;                            // 32 threads per 256-ch row
    bfrag_t pack;
    if (row < NVOX) {
      const float4* fp = (const float4*)f;
      float4 a = fp[2 * t];
      float4 bb = fp[2 * t + 1];
      float v[8] = {a.x, a.y, a.z, a.w, bb.x, bb.y, bb.z, bb.w};
#pragma unroll
      for (int i = 0; i < 8; ++i) pack[i] = (short)f2bf(v[i]);
    } else {
#pragma unroll
      for (int i = 0; i < 8; ++i) pack[i] = 0;
    }
    *(bfrag_t*)(o + (size_t)t * 8) = pack;
  } else {
    int t = (b - NPAD * CCH / 8 / 256) * 256 + threadIdx.x;  // 0..589823
    int g9 = t >> 16;                        // conv*3+tap, 0..8
    int idx = t & 65535;
    int n = idx >> 8, k = idx & 255;
    const float* w = (g9 < 3) ? w1 : ((g9 < 6) ? w2 : w3);
    int tap = (g9 < 3) ? g9 : ((g9 < 6) ? g9 - 3 : g9 - 6);
    wo[t] = f2bf(w[(tap * 256 + k) * 256 + n]);
    if (t < 6) tcnt[t] = 0;
  }
}

// ---- build per-tap compacted pair lists + per-(64-row-block,conv) hit lists ----
// tap order: 0:x-1 1:x+1 2:y-1 3:y+1 4:z-1 5:z+1
// pairs[tap][p] = source row.  hits[(rb*3+c)*HCAP + i] = row(6b)|sm(13b)|sp(13b),
// hcnt[rb*3+c] = count. One wave == one 64-row recon block -> ballot compaction.
__global__ __launch_bounds__(256) void build_kernel(
    const int* __restrict__ nbrx, const int* __restrict__ nbry,
    const int* __restrict__ nbrz,
    int* __restrict__ pairs, int* __restrict__ tcnt,
    unsigned int* __restrict__ hits, int* __restrict__ hcnt) {
  __shared__ int wcnt[4], wbase[4];
  int r = blockIdx.x * 256 + threadIdx.x;
  const int lane = threadIdx.x & 63, w = threadIdx.x >> 6;
  bool act = (r < NVOX);
  int nb[6];
  nb[0] = act ? nbrx[r * 3]     : -1;
  nb[1] = act ? nbrx[r * 3 + 2] : -1;
  nb[2] = act ? nbry[r * 3]     : -1;
  nb[3] = act ? nbry[r * 3 + 2] : -1;
  nb[4] = act ? nbrz[r * 3]     : -1;
  nb[5] = act ? nbrz[r * 3 + 2] : -1;
  int slot[6];
  for (int t = 0; t < 6; ++t) {
    bool h = nb[t] >= 0;
    unsigned long long b = __ballot(h);
    int pfx = __popcll(b & ((1ull << lane) - 1ull));
    if (lane == 0) wcnt[w] = __popcll(b);
    __syncthreads();
    if (threadIdx.x == 0) {
      int tot = wcnt[0] + wcnt[1] + wcnt[2] + wcnt[3];
      int base = tot ? atomicAdd(&tcnt[t], tot) : 0;
      wbase[0] = base;
      wbase[1] = base + wcnt[0];
      wbase[2] = base + wcnt[0] + wcnt[1];
      wbase[3] = base + wcnt[0] + wcnt[1] + wcnt[2];
    }
    __syncthreads();
    slot[t] = ZSLOT;
    if (h) {
      int p = wbase[w] + pfx;
      if (p < CAP) {
        pairs[t * CAP + p] = nb[t];
        slot[t] = p;
      }
    }
    __syncthreads();  // WAR on wcnt/wbase before next tap
  }
  // per-conv merged hit lists (wave covers rows [rb*64, rb*64+64))
  const int rb = blockIdx.x * 4 + w;
#pragma unroll
  for (int c = 0; c < 3; ++c) {
    int sm = slot[2 * c], sp = slot[2 * c + 1];
    bool hit = act && (sm != ZSLOT || sp != ZSLOT);
    unsigned long long b = __ballot(hit);
    int pfx = __popcll(b & ((1ull << lane) - 1ull));
    if (hit && pfx < HCAP)
      hits[(rb * 3 + c) * HCAP + pfx] =
          (unsigned)lane | ((unsigned)sm << 6) | ((unsigned)sp << 19);
    if (lane == 0) {
      int n = __popcll(b);
      hcnt[rb * 3 + c] = n < HCAP ? n : HCAP;
    }
  }
}

// ---- sparse tap GEMM: Ytap[tap][slot][:] = f16[src] . W[tap]  (bf16 out) ----
// grid (CAPP/64, 6); slots >= count gather ZROW -> zero output rows (incl ZSLOT)
__global__ __launch_bounds__(512, 2) void sparse_kernel(
    const unsigned short* __restrict__ F16, const unsigned short* __restrict__ Wt,
    const int* __restrict__ pairs, const int* __restrict__ tcnt,
    unsigned short* __restrict__ Ytap) {
  __shared__ unsigned short As[64 * 256];  // 32 KB, XOR-swizzled
  const int tid = threadIdx.x;
  const int w = tid >> 6, lane = tid & 63;
  const int m = lane & 15, quad = lane >> 4;
  const int half = lane >> 5;
  const int lrb = w << 3;
  const int tap = blockIdx.y;
  const int p0 = blockIdx.x * 64;
  const int cnt0 = tcnt[tap];
  const int cnt = cnt0 < CAP ? cnt0 : CAP;

#pragma unroll
  for (int iss = 0; iss < 4; ++iss) {
    int lr = lrb + (iss << 1) + half;
    int p = p0 + lr;
    int src = (p < cnt) ? pairs[tap * CAP + p] : -1;
    int srow = (src >= 0) ? src : ZROW;
    int clog = (lane & 31) ^ (lr & 31);
    async_copy16(F16 + ((size_t)srow << 8) + (clog << 3),
                 (char*)As + ((size_t)(lrb + (iss << 1)) << 9));
  }
  __syncthreads();

  const int g9 = (tap >> 1) * 3 + ((tap & 1) << 1);  // conv*3 + {0,2}
  const unsigned short* Wtap = Wt + ((size_t)g9 << 16);
  accfrag_t acc[4][2];
#pragma unroll
  for (int mt = 0; mt < 4; ++mt)
#pragma unroll
    for (int nt = 0; nt < 2; ++nt) acc[mt][nt] = (accfrag_t){0.f, 0.f, 0.f, 0.f};

#pragma unroll
  for (int ks = 0; ks < 8; ++ks) {
    bfrag_t a[4], bb[2];
#pragma unroll
    for (int mt = 0; mt < 4; ++mt) {
      int row = mt * 16 + m;
      int phys = ((ks << 2) + quad) ^ (row & 31);
      a[mt] = *(const bfrag_t*)((const char*)As + row * 512 + phys * 16);
    }
#pragma unroll
    for (int nt = 0; nt < 2; ++nt) {
      int col = (w << 5) + nt * 16 + m;
      bb[nt] = *(const bfrag_t*)(Wtap + col * 256 + (ks << 5) + (quad << 3));
    }
#pragma unroll
    for (int mt = 0; mt < 4; ++mt)
#pragma unroll
      for (int nt = 0; nt < 2; ++nt)
        acc[mt][nt] = __builtin_amdgcn_mfma_f32_16x16x32_bf16(
            a[mt], bb[nt], acc[mt][nt], 0, 0, 0);
  }

#pragma unroll
  for (int mt = 0; mt < 4; ++mt)
#pragma unroll
    for (int r = 0; r < 4; ++r) {
      int slot = p0 + mt * 16 + quad * 4 + r;
#pragma unroll
      for (int nt = 0; nt < 2; ++nt) {
        int col = (w << 5) + nt * 16 + m;
        Ytap[((size_t)tap * CAPP + slot) * 256 + col] = f2bf(acc[mt][nt][r]);
      }
    }
}

// ---- main: dense center GEMM (A staged once, 3 convs reuse it) + hit-list
//      sparse apply via LDS (runtime row indexing lives in LDS, not regs)
//      + BN+sigmoid + gate. ----
__global__ __launch_bounds__(512) void recon_kernel(
    const unsigned short* __restrict__ F16, const float* __restrict__ F32,
    const unsigned short* __restrict__ Wt,
    const unsigned short* __restrict__ Ytap,
    const unsigned int* __restrict__ hits, const int* __restrict__ hcnt,
    const float* __restrict__ g1, const float* __restrict__ b1,
    const float* __restrict__ g2, const float* __restrict__ b2,
    const float* __restrict__ g3, const float* __restrict__ b3,
    float* __restrict__ out) {
  __shared__ unsigned short As[64 * 256];  // 32 KB, XOR-swizzled
  __shared__ float Yl[256 * 68];           // 68 KB, col-major [col][row], pad 64->68
  const int tid = threadIdx.x;
  const int w = tid >> 6, lane = tid & 63;
  const int m = lane & 15, quad = lane >> 4;
  const int half = lane >> 5;
  const int lrb = w << 3;
  // XCD-aware bijective swizzle (2344 = 8*293)
  const int bid = blockIdx.x;
  const int bsw = (bid & 7) * (GRIDX / 8) + (bid >> 3);
  const int m0 = bsw * 64;
  const int rb3 = bsw * 3;
  const float RSQ = 0.9999950000374998f;  // rsqrt(1+1e-5)

  accfrag_t sum[4][2];
#pragma unroll
  for (int mt = 0; mt < 4; ++mt)
#pragma unroll
    for (int nt = 0; nt < 2; ++nt) sum[mt][nt] = (accfrag_t){0.f, 0.f, 0.f, 0.f};

  // stage identity rows once + zero-init Yl (this thread's 32 cells)
#pragma unroll
  for (int iss = 0; iss < 4; ++iss) {
    int lr = lrb + (iss << 1) + half;
    int srow = m0 + lr;
    int clog = (lane & 31) ^ (lr & 31);
    async_copy16(F16 + ((size_t)srow << 8) + (clog << 3),
                 (char*)As + ((size_t)(lrb + (iss << 1)) << 9));
  }
#pragma unroll
  for (int mt = 0; mt < 4; ++mt)
#pragma unroll
    for (int nt = 0; nt < 2; ++nt) {
      int col = (w << 5) + nt * 16 + m;
      *(float4*)&Yl[col * 68 + mt * 16 + quad * 4] = make_float4(0.f, 0.f, 0.f, 0.f);
    }
  __syncthreads();

  for (int conv = 0; conv < 3; ++conv) {
    const unsigned short* Wc = Wt + ((size_t)(conv * 3 + 1) << 16);  // center
    accfrag_t acc[4][2];
#pragma unroll
    for (int mt = 0; mt < 4; ++mt)
#pragma unroll
      for (int nt = 0; nt < 2; ++nt) acc[mt][nt] = (accfrag_t){0.f, 0.f, 0.f, 0.f};

    __builtin_amdgcn_s_setprio(1);
#pragma unroll
    for (int ks = 0; ks < 8; ++ks) {
      bfrag_t a[4], bb[2];
#pragma unroll
      for (int mt = 0; mt < 4; ++mt) {
        int row = mt * 16 + m;
        int phys = ((ks << 2) + quad) ^ (row & 31);
        a[mt] = *(const bfrag_t*)((const char*)As + row * 512 + phys * 16);
      }
#pragma unroll
      for (int nt = 0; nt < 2; ++nt) {
        int col = (w << 5) + nt * 16 + m;
        bb[nt] = *(const bfrag_t*)(Wc + col * 256 + (ks << 5) + (quad << 3));
      }
#pragma unroll
      for (int mt = 0; mt < 4; ++mt)
#pragma unroll
        for (int nt = 0; nt < 2; ++nt)
          acc[mt][nt] = __builtin_amdgcn_mfma_f32_16x16x32_bf16(
              a[mt], bb[nt], acc[mt][nt], 0, 0, 0);
    }
    __builtin_amdgcn_s_setprio(0);

    // hit apply: only the ~3.5 rows with sparse contributions touch global.
    // lane l covers channels 4l..4l+3 of the hit row; Yl starts zeroed.
    int cnt = hcnt[rb3 + conv];
    for (int h = w; h < cnt; h += 8) {
      unsigned e = hits[(size_t)(rb3 + conv) * HCAP + h];
      int rr = e & 63;
      int sm = (e >> 6) & 8191;
      int sp = e >> 19;
      const ushort4 um = *(const ushort4*)(
          Ytap + ((size_t)(2 * conv) * CAPP + sm) * 256 + (lane << 2));
      const ushort4 up = *(const ushort4*)(
          Ytap + ((size_t)(2 * conv + 1) * CAPP + sp) * 256 + (lane << 2));
      Yl[((lane << 2) + 0) * 68 + rr] = bf2f(um.x) + bf2f(up.x);
      Yl[((lane << 2) + 1) * 68 + rr] = bf2f(um.y) + bf2f(up.y);
      Yl[((lane << 2) + 2) * 68 + rr] = bf2f(um.z) + bf2f(up.z);
      Yl[((lane << 2) + 3) * 68 + rr] = bf2f(um.w) + bf2f(up.w);
    }
    __syncthreads();  // apply visible to all

    // readback (+ clear-on-read) + BN + sigmoid, accumulate
    const float* gp = (conv == 0) ? g1 : ((conv == 1) ? g2 : g3);
    const float* bp = (conv == 0) ? b1 : ((conv == 1) ? b2 : b3);
    float sc[2], bi[2];
#pragma unroll
    for (int nt = 0; nt < 2; ++nt) {
      int c = (w << 5) + nt * 16 + m;
      sc[nt] = gp[c] * RSQ;
      bi[nt] = bp[c];
    }
#pragma unroll
    for (int mt = 0; mt < 4; ++mt)
#pragma unroll
      for (int nt = 0; nt < 2; ++nt) {
        int col = (w << 5) + nt * 16 + m;
        float4 yv = *(float4*)&Yl[col * 68 + mt * 16 + quad * 4];
#pragma unroll
        for (int r = 0; r < 4; ++r) {
          float y = acc[mt][nt][r] + ((const float*)&yv)[r];
          sum[mt][nt][r] += 1.0f / (1.0f + __expf(-(y * sc[nt] + bi[nt])));
        }
        *(float4*)&Yl[col * 68 + mt * 16 + quad * 4] =
            make_float4(0.f, 0.f, 0.f, 0.f);
      }
    __syncthreads();  // clears visible before next conv's apply
  }

  // final gate: out = sum * feats (fp32)
#pragma unroll
  for (int mt = 0; mt < 4; ++mt)
#pragma unroll
    for (int r = 0; r < 4; ++r) {
      int row = m0 + mt * 16 + quad * 4 + r;
      if (row < NVOX) {
#pragma unroll
        for (int nt = 0; nt < 2; ++nt) {
          int c = (w << 5) + nt * 16 + m;
          size_t off = ((size_t)row << 8) + c;
          out[off] = sum[mt][nt][r] * F32[off];
        }
      }
    }
}

extern "C" void kernel_launch(void* const* d_in, const int* in_sizes, int n_in,
                              void* d_out, int out_size, void* d_ws, size_t ws_size,
                              hipStream_t stream) {
  const float* feats = (const float*)d_in[0];
  const float* w1 = (const float*)d_in[1];
  const float* w2 = (const float*)d_in[2];
  const float* w3 = (const float*)d_in[3];
  const float* g1 = (const float*)d_in[4];
  const float* b1 = (const float*)d_in[5];
  const float* g2 = (const float*)d_in[6];
  const float* b2 = (const float*)d_in[7];
  const float* g3 = (const float*)d_in[8];
  const float* b3 = (const float*)d_in[9];
  const int* nbrx = (const int*)d_in[10];
  const int* nbry = (const int*)d_in[11];
  const int* nbrz = (const int*)d_in[12];
  float* out = (float*)d_out;

  // ws layout (all offsets >=64B-aligned):
  //   F16   : NPAD*256 bf16             = 76.81 MB
  //   Wt    : 9*65536 bf16              =  1.18 MB
  //   Ytap  : 6*CAPP*256 bf16           = 14.36 MB
  //   pairs : 6*CAP int32               =  0.11 MB
  //   tcnt  : 64 int32
  //   hits  : GRIDX*3*HCAP uint32       =  0.90 MB
  //   hcnt  : GRIDX*3 int32             =  0.03 MB
  unsigned short* F16 = (unsigned short*)d_ws;
  unsigned short* Wt = F16 + (size_t)NPAD * CCH;
  unsigned short* Ytap = Wt + (size_t)9 * 65536;
  int* pairs = (int*)(Ytap + (size_t)6 * CAPP * 256);
  int* tcnt = pairs + (size_t)6 * CAP;
  unsigned int* hits = (unsigned int*)(tcnt + 64);
  int* hcnt = (int*)(hits + (size_t)GRIDX * 3 * HCAP);

  prep_kernel<<<NPAD * CCH / 8 / 256 + 9 * 65536 / 256, 256, 0, stream>>>(
      feats, F16, w1, w2, w3, Wt, tcnt);
  build_kernel<<<NPAD / 256, 256, 0, stream>>>(nbrx, nbry, nbrz,
                                               pairs, tcnt, hits, hcnt);
  dim3 sgrid(CAPP / 64, 6);
  sparse_kernel<<<sgrid, 512, 0, stream>>>(F16, Wt, pairs, tcnt, Ytap);
  dim3 grid(GRIDX);
  recon_kernel<<<grid, 512, 0, stream>>>(F16, feats, Wt, Ytap, hits, hcnt,
                                         g1, b1, g2, b2, g3, b3, out);
}